// Round 7
// baseline (103.262 us; speedup 1.0000x reference)
//
#include <hip/hip_runtime.h>
#include <cstddef>

static constexpr int B = 64, T = 64, V = 64, C = 65;
static constexpr int NB = 16;                      // producer blocks per batch
static constexpr float NEG   = -1.0e30f;           // log-space "zero"
static constexpr float LOG2E = 1.44269504088896340736f;
static constexpr float LN2   = 0.69314718055994530942f;

// Raw HW transcendentals: v_exp_f32 = 2^x, v_log_f32 = log2(x).
__device__ __forceinline__ float fexp2(float x) {
    float r; asm("v_exp_f32 %0, %1" : "=v"(r) : "v"(x)); return r;
}
__device__ __forceinline__ float flog2(float x) {
    float r; asm("v_log_f32 %0, %1" : "=v"(r) : "v"(x)); return r;
}
// lane i <- lane i-1; lane 0 <- NEG sentinel (folded into the DPP `old`).
__device__ __forceinline__ float shr1(float x, int negi) {
    return __int_as_float(__builtin_amdgcn_update_dpp(
        negi, __float_as_int(x), 0x138 /*wave_shr:1*/, 0xf, 0xf, false));
}

// 126-step anti-diagonal chain for one batch. Scores come as packed float4
// {del,ins,sub,pad} per (t,v) via one dwordx4 prefetch per step (depth-7
// register pipeline, works for global OR LDS pointers). Alpha rows are
// written scattered directly to out (exec-masked, off-chain). Zero LDS.
__device__ __forceinline__ void dp_chain_p(const float4* __restrict__ g4,
                                           float* __restrict__ outb, int v) {
    const int negi = __float_as_int(NEG);
    float a1 = (v == 0) ? 0.0f : NEG;   // own value, previous diagonal
    float a2 = NEG;                     // own value, two diagonals back
    if (v == 0) outb[0] = 0.0f;         // alpha[0][0]

    constexpr int PD = 7;               // 126 = 18*7
    float4 pf[PD];
    #pragma unroll
    for (int k = 0; k < PD; ++k) {
        const int tc = min(max(1 + k - v, 0), T - 1);
        pf[k] = g4[tc * V + v];
    }
    for (int gq = 0; gq < 18; ++gq) {
        #pragma unroll
        for (int k = 0; k < PD; ++k) {
            const int d = gq * PD + 1 + k;
            const float lf1 = shr1(a1, negi);       // alpha[t,   v-1]
            const float lf2 = shr1(a2, negi);       // alpha[t-1, v-1]
            const float xd = pf[k].x + a1;          // del + up
            const float xi = pf[k].y + lf1;         // ins + left
            const float xs = pf[k].z + lf2;         // sub + diag
            {   // prefetch step d+PD (clamped reads stay in-batch; junk unused)
                const int tc = min(max(d + PD - v, 0), T - 1);
                pf[k] = g4[tc * V + v];
            }
            const float m = fmaxf(fmaxf(xd, xs), xi);           // v_max3_f32
            const float s = fexp2(xd - m) + fexp2(xs - m) + fexp2(xi - m);
            const float a = m + flog2(s);
            const int t = d - v;
            if (t >= 0 && t < T) outb[t * V + v] = a * LN2;     // masked store
            a2 = a1; a1 = a;
        }
    }
}

// ---- Fused kernel: 16 gather blocks/batch, ZERO LDS (so 4 blocks/CU and
// all 1024 blocks co-resident). Last arriver per batch runs the DP. ----
__global__ void __launch_bounds__(256, 4) fused_kernel(
    const float* __restrict__ as,
    const int* __restrict__ del_ids,    // [B,T]
    const int* __restrict__ ins_ids,    // [B,V]
    const int* __restrict__ sub_ids,    // [B,T,V]
    float* __restrict__ g,              // [B][T][V][4] = 4 MiB (ws)
    int* __restrict__ flags,            // [B] (ws, memset to 0)
    float* __restrict__ out)
{
    __shared__ int isLast;
    const int b = blockIdx.x >> 4, j = blockIdx.x & (NB - 1);
    const int tid = threadIdx.x;
    float* __restrict__ gf = g + (size_t)b * (T * V * 4);

    // Phase 1: 3 picks/thread. Issue the 3 id-loads, then the 3 independent
    // scattered as-loads (two latency hops, no dependent chain).
    {
        int    pp[3];
        size_t ga[3];
        #pragma unroll
        for (int k = 0; k < 3; ++k) {
            const int p = j * 768 + k * 256 + tid;   // [0,12288), kind-major
            const int kind = p >> 12;                // wave-uniform (64 | 4096)
            const int t = (p >> 6) & 63, v = p & 63;
            int id;
            if (kind == 0)      id = del_ids[b * T + t];   // scalar load
            else if (kind == 1) id = ins_ids[b * V + v];   // coalesced
            else                id = sub_ids[(b * T + t) * V + v];
            pp[k] = (t * V + v) * 4 + kind;
            ga[k] = (size_t)((b * T + t) * V + v) * C + id;
        }
        #pragma unroll
        for (int k = 0; k < 3; ++k)
            gf[pp[k]] = as[ga[k]] * LOG2E;           // log2-domain scores
    }
    __syncthreads();
    if (tid == 0) {
        __threadfence();                             // release g-writes
        isLast = (atomicAdd(flags + b, 1) == NB - 1);
        if (isLast) __threadfence();                 // acquire others' writes
    }
    __syncthreads();
    if (!isLast) return;

    // Phase 2: last arriver runs batch b's DP straight out of L2/IC-warm g.
    if (tid < 64) dp_chain_p((const float4*)gf, out + b * (T * V), tid);
}

// ---- Fallback (ws too small): one block per batch, LDS-packed scores. ----
__global__ void __launch_bounds__(256) mono_kernel(
    const float* __restrict__ as,
    const int* __restrict__ del_ids, const int* __restrict__ ins_ids,
    const int* __restrict__ sub_ids, float* __restrict__ out)
{
    __shared__ __align__(16) float4 sc4[T * V];      // 64 KB {d,i,s,pad}
    const int b = blockIdx.x, tid = threadIdx.x;
    float* sf = (float*)sc4;
    for (int p = tid; p < 3 * T * V; p += 256) {
        const int kind = p >> 12;
        const int t = (p >> 6) & 63, v = p & 63;
        int id;
        if (kind == 0)      id = del_ids[b * T + t];
        else if (kind == 1) id = ins_ids[b * V + v];
        else                id = sub_ids[(b * T + t) * V + v];
        sf[(t * V + v) * 4 + kind] =
            as[(size_t)((b * T + t) * V + v) * C + id] * LOG2E;
    }
    __syncthreads();
    if (tid < 64) dp_chain_p(sc4, out + b * (T * V), tid);
}

extern "C" void kernel_launch(void* const* d_in, const int* in_sizes, int n_in,
                              void* d_out, int out_size, void* d_ws, size_t ws_size,
                              hipStream_t stream) {
    const float* as      = (const float*)d_in[0];
    const int*   del_ids = (const int*)d_in[1];
    const int*   ins_ids = (const int*)d_in[2];
    const int*   sub_ids = (const int*)d_in[3];
    float*       out     = (float*)d_out;
    const size_t gbytes  = (size_t)B * T * V * 4 * sizeof(float);   // 4 MiB

    if (ws_size >= gbytes + 64 * sizeof(int)) {
        float* g     = (float*)d_ws;
        int*   flags = (int*)((char*)d_ws + gbytes);
        hipMemsetAsync(flags, 0, 64 * sizeof(int), stream);
        fused_kernel<<<B * NB, 256, 0, stream>>>(as, del_ids, ins_ids, sub_ids,
                                                 g, flags, out);
    } else {
        mono_kernel<<<B, 256, 0, stream>>>(as, del_ids, ins_ids, sub_ids, out);
    }
}

// Round 8
// 24.753 us; speedup vs baseline: 4.1717x; 4.1717x over previous
//
#include <hip/hip_runtime.h>
#include <cstddef>

static constexpr int B = 64, T = 64, V = 64, C = 65;
static constexpr float NEG   = -1.0e30f;           // log-space "zero"
static constexpr float LOG2E = 1.44269504088896340736f;
static constexpr float LN2   = 0.69314718055994530942f;

// Raw HW transcendentals: v_exp_f32 = 2^x, v_log_f32 = log2(x).
__device__ __forceinline__ float fexp2(float x) {
    float r; asm("v_exp_f32 %0, %1" : "=v"(r) : "v"(x)); return r;
}
__device__ __forceinline__ float flog2(float x) {
    float r; asm("v_log_f32 %0, %1" : "=v"(r) : "v"(x)); return r;
}
// lane i <- lane i-1; lane 0 <- NEG sentinel (folded into the DPP `old`).
__device__ __forceinline__ float shr1(float x, int negi) {
    return __int_as_float(__builtin_amdgcn_update_dpp(
        negi, __float_as_int(x), 0x138 /*wave_shr:1*/, 0xf, 0xf, false));
}

// ---- Gather: round-4 verbatim (measured ~4+ TB/s on the 50 MB scatter).
// One block per (b,t), 3 waves = {del, ins, sub}; 1 pick per thread;
// 12288 independent waves -> max memory-level parallelism.
__global__ void __launch_bounds__(192) gather_kernel(
    const float* __restrict__ as,
    const int* __restrict__ del_ids,   // [B,T]
    const int* __restrict__ ins_ids,   // [B,V]
    const int* __restrict__ sub_ids,   // [B,T,V]
    float* __restrict__ g)             // [B][3][T*V]
{
    const int bt = blockIdx.x, b = bt >> 6, t = bt & 63;
    const int tid = threadIdx.x, v = tid & 63, kind = tid >> 6; // wave-uniform
    int id;
    if (kind == 0)      id = del_ids[bt];
    else if (kind == 1) id = ins_ids[b * V + v];
    else                id = sub_ids[bt * V + v];
    g[((b * 3 + kind) * T + t) * V + v] =
        as[(size_t)(bt * V + v) * C + id] * LOG2E;   // log2-domain scores
}

// 126-step anti-diagonal chain, one wave, log2-domain, depth-7 LDS prefetch
// (7 x ~45 cy compute > 120 cy LDS latency -> reads fully off the chain).
// Alpha stored diagonal-major; inactive lanes' garbage lands in never-read slots.
__device__ __forceinline__ void dp_chain(const float* __restrict__ sc,
                                         float* __restrict__ sAd, int v) {
    const int negi = __float_as_int(NEG);
    float a1 = (v == 0) ? 0.0f : NEG;
    float a2 = NEG;
    constexpr int PD = 7;                           // 126 = 17*7 + 7
    float pD[PD], pI[PD], pS[PD];
    #pragma unroll
    for (int k = 0; k < PD; ++k) {
        const int tc = min(max(1 + k - v, 0), T - 1);
        const int off = tc * V + v;
        pD[k] = sc[off]; pI[k] = sc[T*V + off]; pS[k] = sc[2*T*V + off];
    }
    for (int gq = 0; gq < 17; ++gq) {
        #pragma unroll
        for (int k = 0; k < PD; ++k) {
            const int d = gq * PD + 1 + k;
            const float lf1 = shr1(a1, negi);       // alpha[t,   v-1]
            const float lf2 = shr1(a2, negi);       // alpha[t-1, v-1]
            const float xd = pD[k] + a1;
            const float xs = pS[k] + lf2;
            const float xi = pI[k] + lf1;
            {   // prefetch step d+PD (needed ~315 cy later)
                const int tc = min(max(d + PD - v, 0), T - 1);
                const int off = tc * V + v;
                pD[k] = sc[off]; pI[k] = sc[T*V + off]; pS[k] = sc[2*T*V + off];
            }
            const float m = fmaxf(fmaxf(xd, xs), xi);           // v_max3_f32
            const float s = fexp2(xd - m) + fexp2(xs - m) + fexp2(xi - m);
            const float a = m + flog2(s);
            sAd[d * V + v] = a;                     // unconditional, off-chain
            a2 = a1; a1 = a;
        }
    }
    #pragma unroll
    for (int k = 0; k < PD; ++k) {                  // epilogue d = 120..126
        const int d = 120 + k;
        const float lf1 = shr1(a1, negi);
        const float lf2 = shr1(a2, negi);
        const float xd = pD[k] + a1;
        const float xs = pS[k] + lf2;
        const float xi = pI[k] + lf1;
        const float m = fmaxf(fmaxf(xd, xs), xi);
        const float s = fexp2(xd - m) + fexp2(xs - m) + fexp2(xi - m);
        const float a = m + flog2(s);
        sAd[d * V + v] = a;
        a2 = a1; a1 = a;
    }
}

// ---- DP kernel: 512 threads (8 waves) so stage/writeout halve their
// exposed latency; only wave 0 runs the serial chain. ----
__global__ void __launch_bounds__(512) dp_kernel(
    const float* __restrict__ g, float* __restrict__ out)
{
    __shared__ __align__(16) float sc[3 * T * V];   // 48 KB, [kind][t][v]
    __shared__ __align__(16) float sAd[128 * V];    // 32 KB, diag-major alpha
    const int b = blockIdx.x, tid = threadIdx.x;

    {   // stage 48 KB: 6 float4 per thread, one contiguous stream
        const float4* __restrict__ src = (const float4*)(g + (size_t)b * 12288);
        float4* dst = (float4*)sc;
        #pragma unroll
        for (int j = 0; j < 6; ++j) dst[tid + j * 512] = src[tid + j * 512];
    }
    if (tid == 0) sAd[0] = 0.0f;                    // alpha[0][0]
    __syncthreads();
    if (tid < 64) dp_chain(sc, sAd, tid);
    __syncthreads();

    {   // writeout: out[t][v] = sAd[(t+v)*64 + v] * ln2, float4-coalesced
        #pragma unroll
        for (int j = 0; j < 2; ++j) {
            const int idx = tid + j * 512;          // f4 tile 0..1023
            const int t = idx >> 4, v4 = (idx & 15) * 4;
            float4 r;
            r.x = sAd[(t + v4 + 0) * V + v4 + 0] * LN2;
            r.y = sAd[(t + v4 + 1) * V + v4 + 1] * LN2;
            r.z = sAd[(t + v4 + 2) * V + v4 + 2] * LN2;
            r.w = sAd[(t + v4 + 3) * V + v4 + 3] * LN2;
            ((float4*)out)[(size_t)b * 1024 + idx] = r;
        }
    }
}

// ---- Fallback (ws too small): one block per batch, gather into LDS. ----
__global__ void __launch_bounds__(512) mono_kernel(
    const float* __restrict__ as,
    const int* __restrict__ del_ids, const int* __restrict__ ins_ids,
    const int* __restrict__ sub_ids, float* __restrict__ out)
{
    __shared__ __align__(16) float sc[3 * T * V];
    __shared__ __align__(16) float sAd[128 * V];
    const int b = blockIdx.x, tid = threadIdx.x;
    for (int p = tid; p < 3 * T * V; p += 512) {
        const int kind = p >> 12;
        const int t = (p >> 6) & 63, v = p & 63;
        int id;
        if (kind == 0)      id = del_ids[b * T + t];
        else if (kind == 1) id = ins_ids[b * V + v];
        else                id = sub_ids[(b * T + t) * V + v];
        sc[p] = as[(size_t)((b * T + t) * V + v) * C + id] * LOG2E;
    }
    if (tid == 0) sAd[0] = 0.0f;
    __syncthreads();
    if (tid < 64) dp_chain(sc, sAd, tid);
    __syncthreads();
    #pragma unroll
    for (int j = 0; j < 2; ++j) {
        const int idx = tid + j * 512;
        const int t = idx >> 4, v4 = (idx & 15) * 4;
        float4 r;
        r.x = sAd[(t + v4 + 0) * V + v4 + 0] * LN2;
        r.y = sAd[(t + v4 + 1) * V + v4 + 1] * LN2;
        r.z = sAd[(t + v4 + 2) * V + v4 + 2] * LN2;
        r.w = sAd[(t + v4 + 3) * V + v4 + 3] * LN2;
        ((float4*)out)[(size_t)b * 1024 + idx] = r;
    }
}

extern "C" void kernel_launch(void* const* d_in, const int* in_sizes, int n_in,
                              void* d_out, int out_size, void* d_ws, size_t ws_size,
                              hipStream_t stream) {
    const float* as      = (const float*)d_in[0];
    const int*   del_ids = (const int*)d_in[1];
    const int*   ins_ids = (const int*)d_in[2];
    const int*   sub_ids = (const int*)d_in[3];
    float*       out     = (float*)d_out;
    const size_t gbytes  = (size_t)B * 3 * T * V * sizeof(float);   // 3 MiB

    if (ws_size >= gbytes) {
        float* g = (float*)d_ws;
        gather_kernel<<<B * T, 192, 0, stream>>>(as, del_ids, ins_ids, sub_ids, g);
        dp_kernel<<<B, 512, 0, stream>>>(g, out);
    } else {
        mono_kernel<<<B, 512, 0, stream>>>(as, del_ids, ins_ids, sub_ids, out);
    }
}